// Round 1
// baseline (5718.588 us; speedup 1.0000x reference)
//
#include <hip/hip_runtime.h>
#include <cstdint>
#include <cstddef>

// Problem constants
#define Lc 6
#define Bc 4
#define Nc 1024
#define Dc 1024
#define Hn 16
#define HDc 64
#define Fc 4096

static constexpr long BND = (long)Bc * Nc * Dc;       // 4,194,304
static constexpr long DD  = (long)Dc * Dc;            // 1,048,576
#define FDl  ((long)Fc * Dc)                          // 4,194,304
static constexpr long BNF = (long)Bc * Nc * Fc;       // 16,777,216
static constexpr long SHN = (long)Bc * Hn * Nc * Nc;  // 67,108,864

typedef __attribute__((ext_vector_type(8))) short bf8_t;
typedef __attribute__((ext_vector_type(4))) float f4_t;

__device__ __forceinline__ float b2f(unsigned short u) {
  union { unsigned int i; float f; } v; v.i = ((unsigned int)u) << 16; return v.f;
}
__device__ __forceinline__ unsigned short f2b(float f) {
  union { float f; unsigned int i; } v; v.f = f;
  return (unsigned short)((v.i + 0x7fffu + ((v.i >> 16) & 1u)) >> 16);
}

__device__ __forceinline__ void gl_lds16(const unsigned short* g, unsigned short* l) {
  __builtin_amdgcn_global_load_lds(
      (const __attribute__((address_space(1))) void*)g,
      (__attribute__((address_space(3))) void*)l, 16, 0, 0);
}

// ---------------- fp32 -> bf16 cast ----------------
__global__ __launch_bounds__(256) void k_cast(const float* __restrict__ x,
                                              unsigned short* __restrict__ y, long n4) {
  long i = (long)blockIdx.x * 256 + threadIdx.x;
  if (i >= n4) return;
  float4 v = ((const float4*)x)[i];
  ushort4 o = { f2b(v.x), f2b(v.y), f2b(v.z), f2b(v.w) };
  ((ushort4*)y)[i] = o;
}

// ---------------- V [B,N,D] -> Vt [B*H, HD, N] ----------------
__global__ __launch_bounds__(256) void k_packvt(const unsigned short* __restrict__ V,
                                                unsigned short* __restrict__ Vt) {
  long idx = (long)blockIdx.x * 256 + threadIdx.x;  // over B*H*HD*N
  int j = (int)(idx & (Nc - 1));
  long t2 = idx >> 10;
  int d = (int)(t2 & (HDc - 1));
  long bh = t2 >> 6;
  int b = (int)(bh >> 4);
  int h = (int)(bh & (Hn - 1));
  Vt[idx] = V[((long)b * Nc + j) * Dc + h * HDc + d];
}

// ---------------- softmax over rows of S [B*H*N, N], mask [N,N] fp32 ----------------
__global__ __launch_bounds__(256) void k_softmax(unsigned short* __restrict__ S,
                                                 const float* __restrict__ mask) {
  const long row = blockIdx.x;
  const int i = (int)(row & (Nc - 1));
  unsigned short* p = S + row * Nc;
  const float4* m4 = (const float4*)(mask + (long)i * Nc);
  const int tid = threadIdx.x;
  const int lane = tid & 63, wave = tid >> 6;

  ushort4 u = ((const ushort4*)p)[tid];
  float4 mv = m4[tid];
  float v0 = b2f(u.x) + mv.x, v1 = b2f(u.y) + mv.y;
  float v2 = b2f(u.z) + mv.z, v3 = b2f(u.w) + mv.w;

  float mx = fmaxf(fmaxf(v0, v1), fmaxf(v2, v3));
  #pragma unroll
  for (int o = 32; o > 0; o >>= 1) mx = fmaxf(mx, __shfl_down(mx, o));
  __shared__ float rm[4];
  if (lane == 0) rm[wave] = mx;
  __syncthreads();
  mx = fmaxf(fmaxf(rm[0], rm[1]), fmaxf(rm[2], rm[3]));

  v0 = __expf(v0 - mx); v1 = __expf(v1 - mx);
  v2 = __expf(v2 - mx); v3 = __expf(v3 - mx);
  float s = v0 + v1 + v2 + v3;
  #pragma unroll
  for (int o = 32; o > 0; o >>= 1) s += __shfl_down(s, o);
  __shared__ float rs[4];
  if (lane == 0) rs[wave] = s;
  __syncthreads();
  s = rs[0] + rs[1] + rs[2] + rs[3];
  float inv = 1.f / s;
  ushort4 o4 = { f2b(v0 * inv), f2b(v1 * inv), f2b(v2 * inv), f2b(v3 * inv) };
  ((ushort4*)p)[tid] = o4;
}

// ---------------- LayerNorm rows of X [B*N, D]; dual fp32+bf16 out ----------------
__global__ __launch_bounds__(256) void k_ln(const float* __restrict__ X,
                                            const float* __restrict__ g,
                                            const float* __restrict__ be,
                                            float* __restrict__ Yf,
                                            unsigned short* __restrict__ Yb) {
  const long row = blockIdx.x;
  const float4* x4 = (const float4*)(X + row * Dc);
  const int tid = threadIdx.x, lane = tid & 63, wave = tid >> 6;
  float4 x = x4[tid];
  float s = x.x + x.y + x.z + x.w;
  float q = x.x * x.x + x.y * x.y + x.z * x.z + x.w * x.w;
  #pragma unroll
  for (int o = 32; o > 0; o >>= 1) { s += __shfl_down(s, o); q += __shfl_down(q, o); }
  __shared__ float rs[4], rq[4];
  if (lane == 0) { rs[wave] = s; rq[wave] = q; }
  __syncthreads();
  s = rs[0] + rs[1] + rs[2] + rs[3];
  q = rq[0] + rq[1] + rq[2] + rq[3];
  const float mean = s * (1.f / Dc);
  const float var = q * (1.f / Dc) - mean * mean;
  const float rstd = rsqrtf(var + 1e-5f);
  float4 gv = ((const float4*)g)[tid];
  float4 bv = ((const float4*)be)[tid];
  float4 y;
  y.x = (x.x - mean) * rstd * gv.x + bv.x;
  y.y = (x.y - mean) * rstd * gv.y + bv.y;
  y.z = (x.z - mean) * rstd * gv.z + bv.z;
  y.w = (x.w - mean) * rstd * gv.w + bv.w;
  if (Yf) ((float4*)(Yf + row * Dc))[tid] = y;
  if (Yb) {
    ushort4 o = { f2b(y.x), f2b(y.y), f2b(y.z), f2b(y.w) };
    ((ushort4*)(Yb + row * Dc))[tid] = o;
  }
}

// ---------------- GEMM: C = A[M,K] * W[Nout,K]^T (+bias)*scale (+relu) (+res) ----------------
// m97 structure: 128-wide tiles, BK=64, global_load_lds(16B) staging, 16x16x32 bf16 MFMA.
// Batched via blockIdx.z: t -> (tb=t/hdiv, th=t%hdiv) with per-(b,h) element strides.
template <int BM, int BN, int MW, int NW>
__global__ __launch_bounds__(256, 2) void gemm_bt(
    const unsigned short* __restrict__ A, const unsigned short* __restrict__ W,
    const float* __restrict__ bias, const float* __restrict__ res,
    float* __restrict__ Cf, unsigned short* __restrict__ Cb,
    int K, int lda, int ldb, int ldc, float scale, int relu,
    long sAb, long sAh, long sBb, long sBh, long sCb, long sCh, int hdiv) {
  constexpr int WM = BM / MW, WN = BN / NW;
  constexpr int FM = WM / 16, FN = WN / 16;

  __shared__ __align__(16) unsigned short As[BM * 64];
  __shared__ __align__(16) unsigned short Bs[BN * 64];

  const int tid = threadIdx.x;
  const int wave = tid >> 6, lane = tid & 63;
  const int wm = wave / NW, wn = wave % NW;
  const int n0 = blockIdx.x * BN, m0 = blockIdx.y * BM;
  const int t = blockIdx.z;
  const int tb = t / hdiv, th = t % hdiv;

  const unsigned short* Ab = A + (long)tb * sAb + (long)th * sAh;
  const unsigned short* Bb = W + (long)tb * sBb + (long)th * sBh;
  const long coff = (long)tb * sCb + (long)th * sCh;

  f4_t acc[FM][FN];
  const f4_t zero = {0.f, 0.f, 0.f, 0.f};
  #pragma unroll
  for (int i = 0; i < FM; ++i)
    #pragma unroll
    for (int j = 0; j < FN; ++j) acc[i][j] = zero;

  const int sr = tid >> 3;         // 0..31
  const int sc = (tid & 7) * 8;    // 0..56 elements
  const int lm = lane & 15, quad = lane >> 4;

  for (int k0 = 0; k0 < K; k0 += 64) {
    #pragma unroll
    for (int it = 0; it < BM / 32; ++it) {
      const int rr = it * 32 + sr;
      gl_lds16(Ab + (long)(m0 + rr) * lda + (k0 + sc), &As[rr * 64 + sc]);
    }
    #pragma unroll
    for (int it = 0; it < BN / 32; ++it) {
      const int rr = it * 32 + sr;
      gl_lds16(Bb + (long)(n0 + rr) * ldb + (k0 + sc), &Bs[rr * 64 + sc]);
    }
    __syncthreads();
    #pragma unroll
    for (int kk = 0; kk < 2; ++kk) {
      const int kq = kk * 32 + quad * 8;
      bf8_t af[FM], bfr[FN];
      #pragma unroll
      for (int i = 0; i < FM; ++i)
        af[i] = *(const bf8_t*)&As[(wm * WM + i * 16 + lm) * 64 + kq];
      #pragma unroll
      for (int j = 0; j < FN; ++j)
        bfr[j] = *(const bf8_t*)&Bs[(wn * WN + j * 16 + lm) * 64 + kq];
      #pragma unroll
      for (int i = 0; i < FM; ++i)
        #pragma unroll
        for (int j = 0; j < FN; ++j)
          acc[i][j] = __builtin_amdgcn_mfma_f32_16x16x32_bf16(af[i], bfr[j], acc[i][j], 0, 0, 0);
    }
    __syncthreads();
  }

  // Epilogue. C/D layout (m89/m91-verified): col = lane&15, row = quad*4 + reg.
  #pragma unroll
  for (int i = 0; i < FM; ++i) {
    const int grow_base = m0 + wm * WM + i * 16 + quad * 4;
    #pragma unroll
    for (int j = 0; j < FN; ++j) {
      const int gcol = n0 + wn * WN + j * 16 + lm;
      const float bi = bias ? bias[gcol] : 0.f;
      #pragma unroll
      for (int r = 0; r < 4; ++r) {
        float v = (acc[i][j][r] + bi) * scale;
        if (relu) v = fmaxf(v, 0.f);
        const long cidx = coff + (long)(grow_base + r) * ldc + gcol;
        if (res) v += res[cidx];
        if (Cf) Cf[cidx] = v;
        if (Cb) Cb[cidx] = f2b(v);
      }
    }
  }
}

extern "C" void kernel_launch(void* const* d_in, const int* in_sizes, int n_in,
                              void* d_out, int out_size, void* d_ws, size_t ws_size,
                              hipStream_t stream) {
  const float* feats    = (const float*)d_in[0];
  const float* enc      = (const float*)d_in[1];
  const float* trg_mask = (const float*)d_in[2];
  const float* src_mask = (const float*)d_in[3];
  const float* wq1 = (const float*)d_in[4];  const float* bq1 = (const float*)d_in[5];
  const float* wk1 = (const float*)d_in[6];  const float* bk1 = (const float*)d_in[7];
  const float* wv1 = (const float*)d_in[8];  const float* bv1 = (const float*)d_in[9];
  const float* wo1 = (const float*)d_in[10]; const float* bo1 = (const float*)d_in[11];
  const float* wq2 = (const float*)d_in[12]; const float* bq2 = (const float*)d_in[13];
  const float* wk2 = (const float*)d_in[14]; const float* bk2 = (const float*)d_in[15];
  const float* wv2 = (const float*)d_in[16]; const float* bv2 = (const float*)d_in[17];
  const float* wo2 = (const float*)d_in[18]; const float* bo2 = (const float*)d_in[19];
  const float* wf1 = (const float*)d_in[20]; const float* bf1 = (const float*)d_in[21];
  const float* wf2 = (const float*)d_in[22]; const float* bf2 = (const float*)d_in[23];
  const float* g1  = (const float*)d_in[24]; const float* be1 = (const float*)d_in[25];
  const float* g2  = (const float*)d_in[26]; const float* be2 = (const float*)d_in[27];
  const float* g3  = (const float*)d_in[28]; const float* be3 = (const float*)d_in[29];
  float* out = (float*)d_out;

  // ---- workspace carve (all 256B aligned) ----
  char* wsp = (char*)d_ws;
  size_t off = 0;
  auto alloc = [&](size_t bytes) -> void* {
    void* p = wsp + off;
    off = (off + bytes + 255) & ~(size_t)255;
    return p;
  };
  unsigned short* wq1b = (unsigned short*)alloc(Lc * DD * 2);
  unsigned short* wk1b = (unsigned short*)alloc(Lc * DD * 2);
  unsigned short* wv1b = (unsigned short*)alloc(Lc * DD * 2);
  unsigned short* wo1b = (unsigned short*)alloc(Lc * DD * 2);
  unsigned short* wq2b = (unsigned short*)alloc(Lc * DD * 2);
  unsigned short* wk2b = (unsigned short*)alloc(Lc * DD * 2);
  unsigned short* wv2b = (unsigned short*)alloc(Lc * DD * 2);
  unsigned short* wo2b = (unsigned short*)alloc(Lc * DD * 2);
  unsigned short* wf1b = (unsigned short*)alloc(Lc * FDl * 2);
  unsigned short* wf2b = (unsigned short*)alloc(Lc * FDl * 2);
  unsigned short* encb  = (unsigned short*)alloc(BND * 2);
  unsigned short* featb = (unsigned short*)alloc(BND * 2);
  unsigned short* xb    = (unsigned short*)alloc(BND * 2);
  unsigned short* y1b   = (unsigned short*)alloc(BND * 2);
  unsigned short* y2b   = (unsigned short*)alloc(BND * 2);
  unsigned short* qb    = (unsigned short*)alloc(BND * 2);
  unsigned short* kb    = (unsigned short*)alloc(BND * 2);
  unsigned short* vb    = (unsigned short*)alloc(BND * 2);
  unsigned short* vtb   = (unsigned short*)alloc(BND * 2);
  unsigned short* ob    = (unsigned short*)alloc(BND * 2);
  unsigned short* hb    = (unsigned short*)alloc(BNF * 2);
  unsigned short* Sb    = (unsigned short*)alloc(SHN * 2);
  float* y1f = (float*)alloc(BND * 4);
  float* y2f = (float*)alloc(BND * 4);
  float* pre = (float*)alloc(BND * 4);
  (void)ws_size; (void)in_sizes; (void)n_in; (void)out_size;

  auto cast = [&](const float* src, unsigned short* dst, long n) {
    long n4 = n / 4;
    k_cast<<<dim3((unsigned)((n4 + 255) / 256)), dim3(256), 0, stream>>>(src, dst, n4);
  };
  // plain (non-batched) GEMM, 128x128 tile
  auto gemm = [&](const unsigned short* A, const unsigned short* Wp, const float* bias,
                  const float* res, float* Cf, unsigned short* Cb,
                  int M, int Nout, int K, int lda, int ldb, int ldc, float scale, int relu) {
    gemm_bt<128, 128, 2, 2><<<dim3(Nout / 128, M / 128, 1), dim3(256), 0, stream>>>(
        A, Wp, bias, res, Cf, Cb, K, lda, ldb, ldc, scale, relu,
        0L, 0L, 0L, 0L, 0L, 0L, 1);
  };
  // S[b,h] = Q[b,h] (N x HD) @ K[b,h]^T  -> Sb [B*H, N, N] bf16
  auto gemm_qk = [&](const unsigned short* Q, const unsigned short* Kp, unsigned short* S) {
    gemm_bt<128, 128, 2, 2><<<dim3(Nc / 128, Nc / 128, Bc * Hn), dim3(256), 0, stream>>>(
        Q, Kp, nullptr, nullptr, nullptr, S, HDc, Dc, Dc, Nc, 1.f, 0,
        (long)Nc * Dc, (long)HDc, (long)Nc * Dc, (long)HDc,
        (long)Hn * Nc * Nc, (long)Nc * Nc, Hn);
  };
  // O[b,h] = P (N x N) @ Vt[b,h]^T (Vt rows are head-dims) -> ob [B,N,D] bf16
  auto gemm_pv = [&](const unsigned short* P, const unsigned short* Vt, unsigned short* O) {
    gemm_bt<128, 64, 4, 1><<<dim3(1, Nc / 128, Bc * Hn), dim3(256), 0, stream>>>(
        P, Vt, nullptr, nullptr, nullptr, O, Nc, Nc, Nc, Dc, 1.f, 0,
        (long)Hn * Nc * Nc, (long)Nc * Nc, (long)Hn * HDc * Nc, (long)HDc * Nc,
        (long)Nc * Dc, (long)HDc, Hn);
  };
  auto softmax = [&](unsigned short* S, const float* mask) {
    k_softmax<<<dim3(Bc * Hn * Nc), dim3(256), 0, stream>>>(S, mask);
  };
  auto ln = [&](const float* X, const float* gg, const float* bb, float* Yf, unsigned short* Yb) {
    k_ln<<<dim3(Bc * Nc), dim3(256), 0, stream>>>(X, gg, bb, Yf, Yb);
  };
  auto packvt = [&]() {
    k_packvt<<<dim3((unsigned)(BND / 256)), dim3(256), 0, stream>>>(vb, vtb);
  };

  // ---- weight + enc casts (d_ws is re-poisoned before every call) ----
  cast(wq1, wq1b, Lc * DD); cast(wk1, wk1b, Lc * DD);
  cast(wv1, wv1b, Lc * DD); cast(wo1, wo1b, Lc * DD);
  cast(wq2, wq2b, Lc * DD); cast(wk2, wk2b, Lc * DD);
  cast(wv2, wv2b, Lc * DD); cast(wo2, wo2b, Lc * DD);
  cast(wf1, wf1b, Lc * FDl); cast(wf2, wf2b, Lc * FDl);
  cast(enc, encb, BND);

  const float qscale = 0.125f;  // HD^-0.5, applied after bias like the reference

  for (int l = 0; l < Lc; ++l) {
    const float* featl = feats + (long)l * BND;
    cast(featl, featb, BND);
    const unsigned short* kv = (l == 0) ? encb : xb;  // dec_out (bf16)

    // ---- attn1: Q from feat, K/V from enc_out ----
    gemm(featb, wq1b + l * DD, bq1 + l * Dc, nullptr, nullptr, qb,
         Bc * Nc, Dc, Dc, Dc, Dc, Dc, qscale, 0);
    gemm(encb, wk1b + l * DD, bk1 + l * Dc, nullptr, nullptr, kb,
         Bc * Nc, Dc, Dc, Dc, Dc, Dc, 1.f, 0);
    gemm(encb, wv1b + l * DD, bv1 + l * Dc, nullptr, nullptr, vb,
         Bc * Nc, Dc, Dc, Dc, Dc, Dc, 1.f, 0);
    packvt();
    gemm_qk(qb, kb, Sb);
    softmax(Sb, src_mask);
    gemm_pv(Sb, vtb, ob);
    gemm(ob, wo1b + l * DD, bo1 + l * Dc, featl, pre, nullptr,
         Bc * Nc, Dc, Dc, Dc, Dc, Dc, 1.f, 0);
    ln(pre, g1 + l * Dc, be1 + l * Dc, y1f, y1b);

    // ---- attn2: Q from y, K/V from dec_out ----
    gemm(y1b, wq2b + l * DD, bq2 + l * Dc, nullptr, nullptr, qb,
         Bc * Nc, Dc, Dc, Dc, Dc, Dc, qscale, 0);
    gemm(kv, wk2b + l * DD, bk2 + l * Dc, nullptr, nullptr, kb,
         Bc * Nc, Dc, Dc, Dc, Dc, Dc, 1.f, 0);
    gemm(kv, wv2b + l * DD, bv2 + l * Dc, nullptr, nullptr, vb,
         Bc * Nc, Dc, Dc, Dc, Dc, Dc, 1.f, 0);
    packvt();
    gemm_qk(qb, kb, Sb);
    softmax(Sb, trg_mask);
    gemm_pv(Sb, vtb, ob);
    gemm(ob, wo2b + l * DD, bo2 + l * Dc, y1f, pre, nullptr,
         Bc * Nc, Dc, Dc, Dc, Dc, Dc, 1.f, 0);
    ln(pre, g2 + l * Dc, be2 + l * Dc, y2f, y2b);

    // ---- FFN ----
    gemm(y2b, wf1b + l * FDl, bf1 + l * Fc, nullptr, nullptr, hb,
         Bc * Nc, Fc, Dc, Dc, Dc, Fc, 1.f, 1);
    gemm(hb, wf2b + l * FDl, bf2 + l * Dc, y2f, pre, nullptr,
         Bc * Nc, Dc, Fc, Fc, Fc, Dc, 1.f, 0);
    ln(pre, g3 + l * Dc, be3 + l * Dc, out + (long)l * BND, xb);
  }
}

// Round 2
// 4927.620 us; speedup vs baseline: 1.1605x; 1.1605x over previous
//
#include <hip/hip_runtime.h>
#include <cstdint>
#include <cstddef>

// Problem constants
#define Lc 6
#define Bc 4
#define Nc 1024
#define Dc 1024
#define Hn 16
#define HDc 64
#define Fc 4096

static constexpr long BND = (long)Bc * Nc * Dc;       // 4,194,304
static constexpr long DD  = (long)Dc * Dc;            // 1,048,576
#define FDl  ((long)Fc * Dc)                          // 4,194,304
static constexpr long BNF = (long)Bc * Nc * Fc;       // 16,777,216

typedef __attribute__((ext_vector_type(8))) short bf8_t;
typedef __attribute__((ext_vector_type(4))) float f4_t;

__device__ __forceinline__ float b2f(unsigned short u) {
  union { unsigned int i; float f; } v; v.i = ((unsigned int)u) << 16; return v.f;
}
__device__ __forceinline__ unsigned short f2b(float f) {
  union { float f; unsigned int i; } v; v.f = f;
  return (unsigned short)((v.i + 0x7fffu + ((v.i >> 16) & 1u)) >> 16);
}

__device__ __forceinline__ void gl_lds16(const unsigned short* g, unsigned short* l) {
  __builtin_amdgcn_global_load_lds(
      (const __attribute__((address_space(1))) void*)g,
      (__attribute__((address_space(3))) void*)l, 16, 0, 0);
}

// ---------------- fp32 -> bf16 cast ----------------
__global__ __launch_bounds__(256) void k_cast(const float* __restrict__ x,
                                              unsigned short* __restrict__ y, long n4) {
  long i = (long)blockIdx.x * 256 + threadIdx.x;
  if (i >= n4) return;
  float4 v = ((const float4*)x)[i];
  ushort4 o = { f2b(v.x), f2b(v.y), f2b(v.z), f2b(v.w) };
  ((ushort4*)y)[i] = o;
}

// ---------------- V [B,N,D] -> Vt [B*H, HD, N] ----------------
__global__ __launch_bounds__(256) void k_packvt(const unsigned short* __restrict__ V,
                                                unsigned short* __restrict__ Vt) {
  long idx = (long)blockIdx.x * 256 + threadIdx.x;  // over B*H*HD*N
  int j = (int)(idx & (Nc - 1));
  long t2 = idx >> 10;
  int d = (int)(t2 & (HDc - 1));
  long bh = t2 >> 6;
  int b = (int)(bh >> 4);
  int h = (int)(bh & (Hn - 1));
  Vt[idx] = V[((long)b * Nc + j) * Dc + h * HDc + d];
}

// ---------------- LayerNorm rows of X [B*N, D]; dual fp32+bf16 out ----------------
__global__ __launch_bounds__(256) void k_ln(const float* __restrict__ X,
                                            const float* __restrict__ g,
                                            const float* __restrict__ be,
                                            float* __restrict__ Yf,
                                            unsigned short* __restrict__ Yb) {
  const long row = blockIdx.x;
  const float4* x4 = (const float4*)(X + row * Dc);
  const int tid = threadIdx.x, lane = tid & 63, wave = tid >> 6;
  float4 x = x4[tid];
  float s = x.x + x.y + x.z + x.w;
  float q = x.x * x.x + x.y * x.y + x.z * x.z + x.w * x.w;
  #pragma unroll
  for (int o = 32; o > 0; o >>= 1) { s += __shfl_down(s, o); q += __shfl_down(q, o); }
  __shared__ float rs[4], rq[4];
  if (lane == 0) { rs[wave] = s; rq[wave] = q; }
  __syncthreads();
  s = rs[0] + rs[1] + rs[2] + rs[3];
  q = rq[0] + rq[1] + rq[2] + rq[3];
  const float mean = s * (1.f / Dc);
  const float var = q * (1.f / Dc) - mean * mean;
  const float rstd = rsqrtf(var + 1e-5f);
  float4 gv = ((const float4*)g)[tid];
  float4 bv = ((const float4*)be)[tid];
  float4 y;
  y.x = (x.x - mean) * rstd * gv.x + bv.x;
  y.y = (x.y - mean) * rstd * gv.y + bv.y;
  y.z = (x.z - mean) * rstd * gv.z + bv.z;
  y.w = (x.w - mean) * rstd * gv.w + bv.w;
  if (Yf) ((float4*)(Yf + row * Dc))[tid] = y;
  if (Yb) {
    ushort4 o = { f2b(y.x), f2b(y.y), f2b(y.z), f2b(y.w) };
    ((ushort4*)(Yb + row * Dc))[tid] = o;
  }
}

// ---------------- Fused flash attention ----------------
// Grid: (Nc/64, B*H). Block 256 = 4 waves; wave w owns q-rows w*16..w*16+15 of
// the 64-row Q tile. KV tiles of 128. S/P never hit HBM.
// Q pre-scaled by HD^-0.5. Layouts (m89/m91/m120-verified):
//   MFMA C/D: col=lane&15, row=quad*4+reg.  A/B: [m|n = lane&15][k = quad*8+j].
#define QT 64
#define KT 128
#define PRS 132   // P row stride (ushorts): quad -> bank 8*quad partition, ~conflict-free writes
__global__ __launch_bounds__(256, 2) void k_flash(
    const unsigned short* __restrict__ Q,   // [B,N,D] bf16 (pre-scaled)
    const unsigned short* __restrict__ Kg,  // [B,N,D] bf16
    const unsigned short* __restrict__ Vt,  // [B*H, HD, N] bf16
    const float* __restrict__ mask,         // [N,N] fp32
    unsigned short* __restrict__ O) {       // [B,N,D] bf16
  __shared__ __align__(16) unsigned short Qs[QT * 64];    //  8 KB
  __shared__ __align__(16) unsigned short Ks[KT * 64];    // 16 KB
  __shared__ __align__(16) unsigned short Vs[64 * KT];    // 16 KB  [hd][kv]
  __shared__ __align__(16) unsigned short Ps[QT * PRS];   // 16.5 KB

  const int tid = threadIdx.x;
  const int wave = tid >> 6, lane = tid & 63;
  const int lm = lane & 15, quad = lane >> 4;
  const int bh = blockIdx.y;
  const int b = bh >> 4, h = bh & 15;
  const int q0 = blockIdx.x * QT;

  const unsigned short* Qb = Q + ((long)b * Nc + q0) * Dc + h * HDc;
  const unsigned short* Kb = Kg + (long)b * Nc * Dc + h * HDc;
  const unsigned short* Vb = Vt + (long)bh * HDc * Nc;

  // stage Q tile (once): QT rows x 64 cols; 256 thr x 16B = 32 rows/call
  const int sr = tid >> 3, sc = (tid & 7) * 8;
  #pragma unroll
  for (int it = 0; it < QT / 32; ++it)
    gl_lds16(Qb + (long)(it * 32 + sr) * Dc + sc, &Qs[(it * 32 + sr) * 64 + sc]);

  f4_t Oa[4];
  #pragma unroll
  for (int jh = 0; jh < 4; ++jh) Oa[jh] = {0.f, 0.f, 0.f, 0.f};
  float m_run[4], l_run[4];
  #pragma unroll
  for (int r = 0; r < 4; ++r) { m_run[r] = -1e30f; l_run[r] = 0.f; }

  const int row_q = wave * 16 + quad * 4;  // +r
  const int vr = tid >> 4, vc = (tid & 15) * 8;

  for (int t = 0; t < Nc / KT; ++t) {
    // stage K tile [KT][64] and Vt tile [64][KT]
    #pragma unroll
    for (int it = 0; it < KT / 32; ++it)
      gl_lds16(Kb + (long)(t * KT + it * 32 + sr) * Dc + sc, &Ks[(it * 32 + sr) * 64 + sc]);
    #pragma unroll
    for (int it = 0; it < 4; ++it)
      gl_lds16(Vb + (long)(it * 16 + vr) * Nc + t * KT + vc, &Vs[(it * 16 + vr) * KT + vc]);
    __syncthreads();  // B1: staging visible

    // --- QK^T: wave's 16 q-rows x 128 kv-cols ---
    f4_t Sa[8];
    #pragma unroll
    for (int j = 0; j < 8; ++j) Sa[j] = {0.f, 0.f, 0.f, 0.f};
    #pragma unroll
    for (int kk = 0; kk < 2; ++kk) {
      const int kq = kk * 32 + quad * 8;
      bf8_t aq = *(const bf8_t*)&Qs[(wave * 16 + lm) * 64 + kq];
      #pragma unroll
      for (int j = 0; j < 8; ++j) {
        bf8_t bk = *(const bf8_t*)&Ks[(j * 16 + lm) * 64 + kq];
        Sa[j] = __builtin_amdgcn_mfma_f32_16x16x32_bf16(aq, bk, Sa[j], 0, 0, 0);
      }
    }

    // --- mask + online softmax (rows live in (quad,reg); cols in (j,lm)) ---
    float p[8][4], alpha[4];
    #pragma unroll
    for (int r = 0; r < 4; ++r) {
      const float* mrow = mask + (long)(q0 + row_q + r) * Nc + t * KT + lm;
      float sv[8];
      float mt = -1e30f;
      #pragma unroll
      for (int j = 0; j < 8; ++j) { sv[j] = Sa[j][r] + mrow[j * 16]; mt = fmaxf(mt, sv[j]); }
      #pragma unroll
      for (int o = 1; o < 16; o <<= 1) mt = fmaxf(mt, __shfl_xor(mt, o));
      const float mn = fmaxf(m_run[r], mt);
      alpha[r] = __expf(m_run[r] - mn);
      m_run[r] = mn;
      float sp = 0.f;
      #pragma unroll
      for (int j = 0; j < 8; ++j) { float e = __expf(sv[j] - mn); p[j][r] = e; sp += e; }
      #pragma unroll
      for (int o = 1; o < 16; o <<= 1) sp += __shfl_xor(sp, o);
      l_run[r] = l_run[r] * alpha[r] + sp;
    }

    // --- P -> LDS (C-layout scatter; PRS=132 partitions quads across banks) ---
    #pragma unroll
    for (int r = 0; r < 4; ++r)
      #pragma unroll
      for (int j = 0; j < 8; ++j)
        Ps[(row_q + r) * PRS + j * 16 + lm] = f2b(p[j][r]);
    __syncthreads();  // B2: P visible

    // --- O *= alpha; O += P·V ---
    #pragma unroll
    for (int jh = 0; jh < 4; ++jh)
      #pragma unroll
      for (int r = 0; r < 4; ++r) Oa[jh][r] *= alpha[r];
    #pragma unroll
    for (int kk = 0; kk < 4; ++kk) {
      const int kp = kk * 32 + quad * 8;
      bf8_t ap = *(const bf8_t*)&Ps[(wave * 16 + lm) * PRS + kp];
      #pragma unroll
      for (int jh = 0; jh < 4; ++jh) {
        bf8_t bv = *(const bf8_t*)&Vs[(jh * 16 + lm) * KT + kp];
        Oa[jh] = __builtin_amdgcn_mfma_f32_16x16x32_bf16(ap, bv, Oa[jh], 0, 0, 0);
      }
    }
    __syncthreads();  // B3: PV reads done -> next staging may overwrite Ks/Vs; P rewrite safe
  }

  // epilogue: O rows q0+row_q+r, cols h*64 + jh*16 + lm
  #pragma unroll
  for (int r = 0; r < 4; ++r) {
    const float inv = 1.f / l_run[r];
    unsigned short* orow = O + ((long)b * Nc + q0 + row_q + r) * Dc + h * HDc;
    #pragma unroll
    for (int jh = 0; jh < 4; ++jh) orow[jh * 16 + lm] = f2b(Oa[jh][r] * inv);
  }
}

// ---------------- GEMM: C = A[M,K] * W[Nout,K]^T (+bias)*scale (+relu) (+res) ----------------
template <int BM, int BN, int MW, int NW>
__global__ __launch_bounds__(256, 2) void gemm_bt(
    const unsigned short* __restrict__ A, const unsigned short* __restrict__ W,
    const float* __restrict__ bias, const float* __restrict__ res,
    float* __restrict__ Cf, unsigned short* __restrict__ Cb,
    int K, int lda, int ldb, int ldc, float scale, int relu) {
  constexpr int WM = BM / MW, WN = BN / NW;
  constexpr int FM = WM / 16, FN = WN / 16;

  __shared__ __align__(16) unsigned short As[BM * 64];
  __shared__ __align__(16) unsigned short Bs[BN * 64];

  const int tid = threadIdx.x;
  const int wave = tid >> 6, lane = tid & 63;
  const int wm = wave / NW, wn = wave % NW;
  const int n0 = blockIdx.x * BN, m0 = blockIdx.y * BM;

  f4_t acc[FM][FN];
  const f4_t zero = {0.f, 0.f, 0.f, 0.f};
  #pragma unroll
  for (int i = 0; i < FM; ++i)
    #pragma unroll
    for (int j = 0; j < FN; ++j) acc[i][j] = zero;

  const int sr = tid >> 3;
  const int sc = (tid & 7) * 8;
  const int lm = lane & 15, quad = lane >> 4;

  for (int k0 = 0; k0 < K; k0 += 64) {
    #pragma unroll
    for (int it = 0; it < BM / 32; ++it) {
      const int rr = it * 32 + sr;
      gl_lds16(A + (long)(m0 + rr) * lda + (k0 + sc), &As[rr * 64 + sc]);
    }
    #pragma unroll
    for (int it = 0; it < BN / 32; ++it) {
      const int rr = it * 32 + sr;
      gl_lds16(W + (long)(n0 + rr) * ldb + (k0 + sc), &Bs[rr * 64 + sc]);
    }
    __syncthreads();
    #pragma unroll
    for (int kk = 0; kk < 2; ++kk) {
      const int kq = kk * 32 + quad * 8;
      bf8_t af[FM], bfr[FN];
      #pragma unroll
      for (int i = 0; i < FM; ++i)
        af[i] = *(const bf8_t*)&As[(wm * WM + i * 16 + lm) * 64 + kq];
      #pragma unroll
      for (int j = 0; j < FN; ++j)
        bfr[j] = *(const bf8_t*)&Bs[(wn * WN + j * 16 + lm) * 64 + kq];
      #pragma unroll
      for (int i = 0; i < FM; ++i)
        #pragma unroll
        for (int j = 0; j < FN; ++j)
          acc[i][j] = __builtin_amdgcn_mfma_f32_16x16x32_bf16(af[i], bfr[j], acc[i][j], 0, 0, 0);
    }
    __syncthreads();
  }

  #pragma unroll
  for (int i = 0; i < FM; ++i) {
    const int grow_base = m0 + wm * WM + i * 16 + quad * 4;
    #pragma unroll
    for (int j = 0; j < FN; ++j) {
      const int gcol = n0 + wn * WN + j * 16 + lm;
      const float bi = bias ? bias[gcol] : 0.f;
      #pragma unroll
      for (int r = 0; r < 4; ++r) {
        float v = (acc[i][j][r] + bi) * scale;
        if (relu) v = fmaxf(v, 0.f);
        const long cidx = (long)(grow_base + r) * ldc + gcol;
        if (res) v += res[cidx];
        if (Cf) Cf[cidx] = v;
        if (Cb) Cb[cidx] = f2b(v);
      }
    }
  }
}

extern "C" void kernel_launch(void* const* d_in, const int* in_sizes, int n_in,
                              void* d_out, int out_size, void* d_ws, size_t ws_size,
                              hipStream_t stream) {
  const float* feats    = (const float*)d_in[0];
  const float* enc      = (const float*)d_in[1];
  const float* trg_mask = (const float*)d_in[2];
  const float* src_mask = (const float*)d_in[3];
  const float* wq1 = (const float*)d_in[4];  const float* bq1 = (const float*)d_in[5];
  const float* wk1 = (const float*)d_in[6];  const float* bk1 = (const float*)d_in[7];
  const float* wv1 = (const float*)d_in[8];  const float* bv1 = (const float*)d_in[9];
  const float* wo1 = (const float*)d_in[10]; const float* bo1 = (const float*)d_in[11];
  const float* wq2 = (const float*)d_in[12]; const float* bq2 = (const float*)d_in[13];
  const float* wk2 = (const float*)d_in[14]; const float* bk2 = (const float*)d_in[15];
  const float* wv2 = (const float*)d_in[16]; const float* bv2 = (const float*)d_in[17];
  const float* wo2 = (const float*)d_in[18]; const float* bo2 = (const float*)d_in[19];
  const float* wf1 = (const float*)d_in[20]; const float* bf1 = (const float*)d_in[21];
  const float* wf2 = (const float*)d_in[22]; const float* bf2 = (const float*)d_in[23];
  const float* g1  = (const float*)d_in[24]; const float* be1 = (const float*)d_in[25];
  const float* g2  = (const float*)d_in[26]; const float* be2 = (const float*)d_in[27];
  const float* g3  = (const float*)d_in[28]; const float* be3 = (const float*)d_in[29];
  float* out = (float*)d_out;

  // ---- workspace carve ----
  char* wsp = (char*)d_ws;
  size_t off = 0;
  auto alloc = [&](size_t bytes) -> void* {
    void* p = wsp + off;
    off = (off + bytes + 255) & ~(size_t)255;
    return p;
  };
  unsigned short* wq1b = (unsigned short*)alloc(Lc * DD * 2);
  unsigned short* wk1b = (unsigned short*)alloc(Lc * DD * 2);
  unsigned short* wv1b = (unsigned short*)alloc(Lc * DD * 2);
  unsigned short* wo1b = (unsigned short*)alloc(Lc * DD * 2);
  unsigned short* wq2b = (unsigned short*)alloc(Lc * DD * 2);
  unsigned short* wk2b = (unsigned short*)alloc(Lc * DD * 2);
  unsigned short* wv2b = (unsigned short*)alloc(Lc * DD * 2);
  unsigned short* wo2b = (unsigned short*)alloc(Lc * DD * 2);
  unsigned short* wf1b = (unsigned short*)alloc(Lc * FDl * 2);
  unsigned short* wf2b = (unsigned short*)alloc(Lc * FDl * 2);
  unsigned short* encb  = (unsigned short*)alloc(BND * 2);
  unsigned short* featb = (unsigned short*)alloc(BND * 2);
  unsigned short* xb    = (unsigned short*)alloc(BND * 2);
  unsigned short* y1b   = (unsigned short*)alloc(BND * 2);
  unsigned short* y2b   = (unsigned short*)alloc(BND * 2);
  unsigned short* qb    = (unsigned short*)alloc(BND * 2);
  unsigned short* kb    = (unsigned short*)alloc(BND * 2);
  unsigned short* vb    = (unsigned short*)alloc(BND * 2);
  unsigned short* vtb   = (unsigned short*)alloc(BND * 2);
  unsigned short* ob    = (unsigned short*)alloc(BND * 2);
  unsigned short* hb    = (unsigned short*)alloc(BNF * 2);
  float* y1f = (float*)alloc(BND * 4);
  float* y2f = (float*)alloc(BND * 4);
  float* pre = (float*)alloc(BND * 4);
  (void)ws_size; (void)in_sizes; (void)n_in; (void)out_size;

  auto cast = [&](const float* src, unsigned short* dst, long n) {
    long n4 = n / 4;
    k_cast<<<dim3((unsigned)((n4 + 255) / 256)), dim3(256), 0, stream>>>(src, dst, n4);
  };
  auto gemm = [&](const unsigned short* A, const unsigned short* Wp, const float* bias,
                  const float* res, float* Cf, unsigned short* Cb,
                  int M, int Nout, int K, int lda, int ldb, int ldc, float scale, int relu) {
    gemm_bt<128, 128, 2, 2><<<dim3(Nout / 128, M / 128), dim3(256), 0, stream>>>(
        A, Wp, bias, res, Cf, Cb, K, lda, ldb, ldc, scale, relu);
  };
  auto flash = [&](const float* mask) {
    k_flash<<<dim3(Nc / QT, Bc * Hn), dim3(256), 0, stream>>>(qb, kb, vtb, mask, ob);
  };
  auto ln = [&](const float* X, const float* gg, const float* bb, float* Yf, unsigned short* Yb) {
    k_ln<<<dim3(Bc * Nc), dim3(256), 0, stream>>>(X, gg, bb, Yf, Yb);
  };
  auto packvt = [&]() {
    k_packvt<<<dim3((unsigned)(BND / 256)), dim3(256), 0, stream>>>(vb, vtb);
  };

  // ---- weight + enc casts ----
  cast(wq1, wq1b, Lc * DD); cast(wk1, wk1b, Lc * DD);
  cast(wv1, wv1b, Lc * DD); cast(wo1, wo1b, Lc * DD);
  cast(wq2, wq2b, Lc * DD); cast(wk2, wk2b, Lc * DD);
  cast(wv2, wv2b, Lc * DD); cast(wo2, wo2b, Lc * DD);
  cast(wf1, wf1b, Lc * FDl); cast(wf2, wf2b, Lc * FDl);
  cast(enc, encb, BND);

  const float qscale = 0.125f;  // HD^-0.5, applied after bias like the reference

  for (int l = 0; l < Lc; ++l) {
    const float* featl = feats + (long)l * BND;
    cast(featl, featb, BND);
    const unsigned short* kv = (l == 0) ? encb : xb;  // dec_out (bf16)

    // ---- attn1: Q from feat, K/V from enc_out ----
    gemm(featb, wq1b + l * DD, bq1 + l * Dc, nullptr, nullptr, qb,
         Bc * Nc, Dc, Dc, Dc, Dc, Dc, qscale, 0);
    gemm(encb, wk1b + l * DD, bk1 + l * Dc, nullptr, nullptr, kb,
         Bc * Nc, Dc, Dc, Dc, Dc, Dc, 1.f, 0);
    gemm(encb, wv1b + l * DD, bv1 + l * Dc, nullptr, nullptr, vb,
         Bc * Nc, Dc, Dc, Dc, Dc, Dc, 1.f, 0);
    packvt();
    flash(src_mask);
    gemm(ob, wo1b + l * DD, bo1 + l * Dc, featl, pre, nullptr,
         Bc * Nc, Dc, Dc, Dc, Dc, Dc, 1.f, 0);
    ln(pre, g1 + l * Dc, be1 + l * Dc, y1f, y1b);

    // ---- attn2: Q from y, K/V from dec_out ----
    gemm(y1b, wq2b + l * DD, bq2 + l * Dc, nullptr, nullptr, qb,
         Bc * Nc, Dc, Dc, Dc, Dc, Dc, qscale, 0);
    gemm(kv, wk2b + l * DD, bk2 + l * Dc, nullptr, nullptr, kb,
         Bc * Nc, Dc, Dc, Dc, Dc, Dc, 1.f, 0);
    gemm(kv, wv2b + l * DD, bv2 + l * Dc, nullptr, nullptr, vb,
         Bc * Nc, Dc, Dc, Dc, Dc, Dc, 1.f, 0);
    packvt();
    flash(trg_mask);
    gemm(ob, wo2b + l * DD, bo2 + l * Dc, y1f, pre, nullptr,
         Bc * Nc, Dc, Dc, Dc, Dc, Dc, 1.f, 0);
    ln(pre, g2 + l * Dc, be2 + l * Dc, y2f, y2b);

    // ---- FFN ----
    gemm(y2b, wf1b + l * FDl, bf1 + l * Fc, nullptr, nullptr, hb,
         Bc * Nc, Fc, Dc, Dc, Dc, Fc, 1.f, 1);
    gemm(hb, wf2b + l * FDl, bf2 + l * Dc, y2f, pre, nullptr,
         Bc * Nc, Dc, Fc, Fc, Fc, Dc, 1.f, 0);
    ln(pre, g3 + l * Dc, be3 + l * Dc, out + (long)l * BND, xb);
  }
}

// Round 3
// 3984.193 us; speedup vs baseline: 1.4353x; 1.2368x over previous
//
#include <hip/hip_runtime.h>
#include <cstdint>
#include <cstddef>

// Problem constants
#define Lc 6
#define Bc 4
#define Nc 1024
#define Dc 1024
#define Hn 16
#define HDc 64
#define Fc 4096

static constexpr long BND = (long)Bc * Nc * Dc;       // 4,194,304
static constexpr long DD  = (long)Dc * Dc;            // 1,048,576
#define FDl  ((long)Fc * Dc)                          // 4,194,304
static constexpr long BNF = (long)Bc * Nc * Fc;       // 16,777,216

typedef __attribute__((ext_vector_type(8))) short bf8_t;
typedef __attribute__((ext_vector_type(4))) float f4_t;

__device__ __forceinline__ float b2f(unsigned short u) {
  union { unsigned int i; float f; } v; v.i = ((unsigned int)u) << 16; return v.f;
}
__device__ __forceinline__ unsigned short f2b(float f) {
  union { float f; unsigned int i; } v; v.f = f;
  return (unsigned short)((v.i + 0x7fffu + ((v.i >> 16) & 1u)) >> 16);
}

__device__ __forceinline__ void gl_lds16(const unsigned short* g, unsigned short* l) {
  __builtin_amdgcn_global_load_lds(
      (const __attribute__((address_space(1))) void*)g,
      (__attribute__((address_space(3))) void*)l, 16, 0, 0);
}

// ---------------- fp32 -> bf16 cast ----------------
__global__ __launch_bounds__(256) void k_cast(const float* __restrict__ x,
                                              unsigned short* __restrict__ y, long n4) {
  long i = (long)blockIdx.x * 256 + threadIdx.x;
  if (i >= n4) return;
  float4 v = ((const float4*)x)[i];
  ushort4 o = { f2b(v.x), f2b(v.y), f2b(v.z), f2b(v.w) };
  ((ushort4*)y)[i] = o;
}

// ---------------- per-layer weight-pair concat cast: dst[l] = [cast(s1[l]); cast(s2[l])] ----
__global__ __launch_bounds__(256) void k_cast2(const float* __restrict__ s1,
                                               const float* __restrict__ s2,
                                               unsigned short* __restrict__ dst) {
  long i4 = (long)blockIdx.x * 256 + threadIdx.x;   // float4 index over Lc*2*DD/4
  long flat = i4 * 4;
  int l = (int)(flat / (2 * DD));
  long r = flat - (long)l * 2 * DD;
  const float* src = (r < DD) ? (s1 + (long)l * DD + r) : (s2 + (long)l * DD + (r - DD));
  float4 v = *(const float4*)src;
  ushort4 o = { f2b(v.x), f2b(v.y), f2b(v.z), f2b(v.w) };
  *(ushort4*)(dst + flat) = o;
}

// ---------------- per-layer bias-pair concat (fp32): dst[l] = [b1[l]; b2[l]] ----------------
__global__ __launch_bounds__(256) void k_bcat2(const float* __restrict__ b1,
                                               const float* __restrict__ b2,
                                               float* __restrict__ dst) {
  int i = blockIdx.x * 256 + threadIdx.x;  // over Lc*2048
  int l = i >> 11, r = i & 2047;
  dst[i] = (r < 1024) ? b1[l * 1024 + r] : b2[l * 1024 + (r - 1024)];
}

// ---------------- V-section of KV [rows=(b,n), ld=2048, V at col 1024+h*64+d] -> Vt[bh][d][n]
// LDS 64x64 tile transpose; coalesced global read and write.
__global__ __launch_bounds__(256) void k_packvt2(const unsigned short* __restrict__ KV,
                                                 unsigned short* __restrict__ Vt) {
  __shared__ unsigned short T[64][72];
  const int bh = blockIdx.y, b = bh >> 4, h = bh & 15;
  const int n0 = blockIdx.x * 64;
  const int r = threadIdx.x >> 4;          // 0..15
  const int c4 = (threadIdx.x & 15) * 4;   // 0..60
  const unsigned short* src = KV + ((long)b * Nc + n0) * 2048 + 1024 + h * 64;
  #pragma unroll
  for (int it = 0; it < 4; ++it) {
    ushort4 v = *(const ushort4*)&src[(long)(it * 16 + r) * 2048 + c4];
    *(ushort4*)&T[it * 16 + r][c4] = v;
  }
  __syncthreads();
  unsigned short* dst = Vt + (long)bh * HDc * Nc + n0;
  #pragma unroll
  for (int it = 0; it < 4; ++it) {
    const int d = it * 16 + r;
    ushort4 v = { T[c4 + 0][d], T[c4 + 1][d], T[c4 + 2][d], T[c4 + 3][d] };
    *(ushort4*)&dst[(long)d * Nc + c4] = v;
  }
}

// ---------------- LayerNorm rows of X [B*N, D]; dual fp32+bf16 out ----------------
__global__ __launch_bounds__(256) void k_ln(const float* __restrict__ X,
                                            const float* __restrict__ g,
                                            const float* __restrict__ be,
                                            float* __restrict__ Yf,
                                            unsigned short* __restrict__ Yb) {
  const long row = blockIdx.x;
  const float4* x4 = (const float4*)(X + row * Dc);
  const int tid = threadIdx.x, lane = tid & 63, wave = tid >> 6;
  float4 x = x4[tid];
  float s = x.x + x.y + x.z + x.w;
  float q = x.x * x.x + x.y * x.y + x.z * x.z + x.w * x.w;
  #pragma unroll
  for (int o = 32; o > 0; o >>= 1) { s += __shfl_down(s, o); q += __shfl_down(q, o); }
  __shared__ float rs[4], rq[4];
  if (lane == 0) { rs[wave] = s; rq[wave] = q; }
  __syncthreads();
  s = rs[0] + rs[1] + rs[2] + rs[3];
  q = rq[0] + rq[1] + rq[2] + rq[3];
  const float mean = s * (1.f / Dc);
  const float var = q * (1.f / Dc) - mean * mean;
  const float rstd = rsqrtf(var + 1e-5f);
  float4 gv = ((const float4*)g)[tid];
  float4 bv = ((const float4*)be)[tid];
  float4 y;
  y.x = (x.x - mean) * rstd * gv.x + bv.x;
  y.y = (x.y - mean) * rstd * gv.y + bv.y;
  y.z = (x.z - mean) * rstd * gv.z + bv.z;
  y.w = (x.w - mean) * rstd * gv.w + bv.w;
  if (Yf) ((float4*)(Yf + row * Dc))[tid] = y;
  if (Yb) {
    ushort4 o = { f2b(y.x), f2b(y.y), f2b(y.z), f2b(y.w) };
    ((ushort4*)(Yb + row * Dc))[tid] = o;
  }
}

// ---------------- Fused flash attention ----------------
// Grid: (Nc/64, B*H). Block 256 = 4 waves; wave w owns q-rows w*16..w*16+15.
// K is read from the fused KV buffer with row stride ldk (K = cols 0..1023).
#define QT 64
#define KT 128
#define PRS 132
__global__ __launch_bounds__(256, 2) void k_flash(
    const unsigned short* __restrict__ Q,   // [B,N,D] bf16 (pre-scaled), ld=Dc
    const unsigned short* __restrict__ Kg,  // [B,N,*] bf16, row stride ldk
    const unsigned short* __restrict__ Vt,  // [B*H, HD, N] bf16
    const float* __restrict__ mask,         // [N,N] fp32
    unsigned short* __restrict__ O, int ldk) {
  __shared__ __align__(16) unsigned short Qs[QT * 64];
  __shared__ __align__(16) unsigned short Ks[KT * 64];
  __shared__ __align__(16) unsigned short Vs[64 * KT];
  __shared__ __align__(16) unsigned short Ps[QT * PRS];

  const int tid = threadIdx.x;
  const int wave = tid >> 6, lane = tid & 63;
  const int lm = lane & 15, quad = lane >> 4;
  const int bh = blockIdx.y;
  const int b = bh >> 4, h = bh & 15;
  const int q0 = blockIdx.x * QT;

  const unsigned short* Qb = Q + ((long)b * Nc + q0) * Dc + h * HDc;
  const unsigned short* Kb = Kg + (long)b * Nc * ldk + h * HDc;
  const unsigned short* Vb = Vt + (long)bh * HDc * Nc;

  const int sr = tid >> 3, sc = (tid & 7) * 8;
  #pragma unroll
  for (int it = 0; it < QT / 32; ++it)
    gl_lds16(Qb + (long)(it * 32 + sr) * Dc + sc, &Qs[(it * 32 + sr) * 64 + sc]);

  f4_t Oa[4];
  #pragma unroll
  for (int jh = 0; jh < 4; ++jh) Oa[jh] = {0.f, 0.f, 0.f, 0.f};
  float m_run[4], l_run[4];
  #pragma unroll
  for (int r = 0; r < 4; ++r) { m_run[r] = -1e30f; l_run[r] = 0.f; }

  const int row_q = wave * 16 + quad * 4;
  const int vr = tid >> 4, vc = (tid & 15) * 8;

  for (int t = 0; t < Nc / KT; ++t) {
    #pragma unroll
    for (int it = 0; it < KT / 32; ++it)
      gl_lds16(Kb + (long)(t * KT + it * 32 + sr) * ldk + sc, &Ks[(it * 32 + sr) * 64 + sc]);
    #pragma unroll
    for (int it = 0; it < 4; ++it)
      gl_lds16(Vb + (long)(it * 16 + vr) * Nc + t * KT + vc, &Vs[(it * 16 + vr) * KT + vc]);
    __syncthreads();

    f4_t Sa[8];
    #pragma unroll
    for (int j = 0; j < 8; ++j) Sa[j] = {0.f, 0.f, 0.f, 0.f};
    #pragma unroll
    for (int kk = 0; kk < 2; ++kk) {
      const int kq = kk * 32 + quad * 8;
      bf8_t aq = *(const bf8_t*)&Qs[(wave * 16 + lm) * 64 + kq];
      #pragma unroll
      for (int j = 0; j < 8; ++j) {
        bf8_t bk = *(const bf8_t*)&Ks[(j * 16 + lm) * 64 + kq];
        Sa[j] = __builtin_amdgcn_mfma_f32_16x16x32_bf16(aq, bk, Sa[j], 0, 0, 0);
      }
    }

    float p[8][4], alpha[4];
    #pragma unroll
    for (int r = 0; r < 4; ++r) {
      const float* mrow = mask + (long)(q0 + row_q + r) * Nc + t * KT + lm;
      float sv[8];
      float mt = -1e30f;
      #pragma unroll
      for (int j = 0; j < 8; ++j) { sv[j] = Sa[j][r] + mrow[j * 16]; mt = fmaxf(mt, sv[j]); }
      #pragma unroll
      for (int o = 1; o < 16; o <<= 1) mt = fmaxf(mt, __shfl_xor(mt, o));
      const float mn = fmaxf(m_run[r], mt);
      alpha[r] = __expf(m_run[r] - mn);
      m_run[r] = mn;
      float sp = 0.f;
      #pragma unroll
      for (int j = 0; j < 8; ++j) { float e = __expf(sv[j] - mn); p[j][r] = e; sp += e; }
      #pragma unroll
      for (int o = 1; o < 16; o <<= 1) sp += __shfl_xor(sp, o);
      l_run[r] = l_run[r] * alpha[r] + sp;
    }

    #pragma unroll
    for (int r = 0; r < 4; ++r)
      #pragma unroll
      for (int j = 0; j < 8; ++j)
        Ps[(row_q + r) * PRS + j * 16 + lm] = f2b(p[j][r]);
    __syncthreads();

    #pragma unroll
    for (int jh = 0; jh < 4; ++jh)
      #pragma unroll
      for (int r = 0; r < 4; ++r) Oa[jh][r] *= alpha[r];
    #pragma unroll
    for (int kk = 0; kk < 4; ++kk) {
      const int kp = kk * 32 + quad * 8;
      bf8_t ap = *(const bf8_t*)&Ps[(wave * 16 + lm) * PRS + kp];
      #pragma unroll
      for (int jh = 0; jh < 4; ++jh) {
        bf8_t bv = *(const bf8_t*)&Vs[(jh * 16 + lm) * KT + kp];
        Oa[jh] = __builtin_amdgcn_mfma_f32_16x16x32_bf16(ap, bv, Oa[jh], 0, 0, 0);
      }
    }
    __syncthreads();
  }

  #pragma unroll
  for (int r = 0; r < 4; ++r) {
    const float inv = 1.f / l_run[r];
    unsigned short* orow = O + ((long)b * Nc + q0 + row_q + r) * Dc + h * HDc;
    #pragma unroll
    for (int jh = 0; jh < 4; ++jh) orow[jh * 16 + lm] = f2b(Oa[jh][r] * inv);
  }
}

// ---------------- GEMM: C = A[M,K] * W[Nout,K]^T (+bias)*scale (+relu) (+res) ----------------
template <int BM, int BN, int MW, int NW>
__global__ __launch_bounds__(256, 2) void gemm_bt(
    const unsigned short* __restrict__ A, const unsigned short* __restrict__ W,
    const float* __restrict__ bias, const float* __restrict__ res,
    float* __restrict__ Cf, unsigned short* __restrict__ Cb,
    int K, int lda, int ldb, int ldc, float scale, int relu) {
  constexpr int WM = BM / MW, WN = BN / NW;
  constexpr int FM = WM / 16, FN = WN / 16;

  __shared__ __align__(16) unsigned short As[BM * 64];
  __shared__ __align__(16) unsigned short Bs[BN * 64];

  const int tid = threadIdx.x;
  const int wave = tid >> 6, lane = tid & 63;
  const int wm = wave / NW, wn = wave % NW;
  const int n0 = blockIdx.x * BN, m0 = blockIdx.y * BM;

  f4_t acc[FM][FN];
  const f4_t zero = {0.f, 0.f, 0.f, 0.f};
  #pragma unroll
  for (int i = 0; i < FM; ++i)
    #pragma unroll
    for (int j = 0; j < FN; ++j) acc[i][j] = zero;

  const int sr = tid >> 3;
  const int sc = (tid & 7) * 8;
  const int lm = lane & 15, quad = lane >> 4;

  for (int k0 = 0; k0 < K; k0 += 64) {
    #pragma unroll
    for (int it = 0; it < BM / 32; ++it) {
      const int rr = it * 32 + sr;
      gl_lds16(A + (long)(m0 + rr) * lda + (k0 + sc), &As[rr * 64 + sc]);
    }
    #pragma unroll
    for (int it = 0; it < BN / 32; ++it) {
      const int rr = it * 32 + sr;
      gl_lds16(W + (long)(n0 + rr) * ldb + (k0 + sc), &Bs[rr * 64 + sc]);
    }
    __syncthreads();
    #pragma unroll
    for (int kk = 0; kk < 2; ++kk) {
      const int kq = kk * 32 + quad * 8;
      bf8_t af[FM], bfr[FN];
      #pragma unroll
      for (int i = 0; i < FM; ++i)
        af[i] = *(const bf8_t*)&As[(wm * WM + i * 16 + lm) * 64 + kq];
      #pragma unroll
      for (int j = 0; j < FN; ++j)
        bfr[j] = *(const bf8_t*)&Bs[(wn * WN + j * 16 + lm) * 64 + kq];
      #pragma unroll
      for (int i = 0; i < FM; ++i)
        #pragma unroll
        for (int j = 0; j < FN; ++j)
          acc[i][j] = __builtin_amdgcn_mfma_f32_16x16x32_bf16(af[i], bfr[j], acc[i][j], 0, 0, 0);
    }
    __syncthreads();
  }

  #pragma unroll
  for (int i = 0; i < FM; ++i) {
    const int grow_base = m0 + wm * WM + i * 16 + quad * 4;
    #pragma unroll
    for (int j = 0; j < FN; ++j) {
      const int gcol = n0 + wn * WN + j * 16 + lm;
      const float bi = bias ? bias[gcol] : 0.f;
      #pragma unroll
      for (int r = 0; r < 4; ++r) {
        float v = (acc[i][j][r] + bi) * scale;
        if (relu) v = fmaxf(v, 0.f);
        const long cidx = (long)(grow_base + r) * ldc + gcol;
        if (res) v += res[cidx];
        if (Cf) Cf[cidx] = v;
        if (Cb) Cb[cidx] = f2b(v);
      }
    }
  }
}

extern "C" void kernel_launch(void* const* d_in, const int* in_sizes, int n_in,
                              void* d_out, int out_size, void* d_ws, size_t ws_size,
                              hipStream_t stream) {
  const float* feats    = (const float*)d_in[0];
  const float* enc      = (const float*)d_in[1];
  const float* trg_mask = (const float*)d_in[2];
  const float* src_mask = (const float*)d_in[3];
  const float* wq1 = (const float*)d_in[4];  const float* bq1 = (const float*)d_in[5];
  const float* wk1 = (const float*)d_in[6];  const float* bk1 = (const float*)d_in[7];
  const float* wv1 = (const float*)d_in[8];  const float* bv1 = (const float*)d_in[9];
  const float* wo1 = (const float*)d_in[10]; const float* bo1 = (const float*)d_in[11];
  const float* wq2 = (const float*)d_in[12]; const float* bq2 = (const float*)d_in[13];
  const float* wk2 = (const float*)d_in[14]; const float* bk2 = (const float*)d_in[15];
  const float* wv2 = (const float*)d_in[16]; const float* bv2 = (const float*)d_in[17];
  const float* wo2 = (const float*)d_in[18]; const float* bo2 = (const float*)d_in[19];
  const float* wf1 = (const float*)d_in[20]; const float* bf1 = (const float*)d_in[21];
  const float* wf2 = (const float*)d_in[22]; const float* bf2 = (const float*)d_in[23];
  const float* g1  = (const float*)d_in[24]; const float* be1 = (const float*)d_in[25];
  const float* g2  = (const float*)d_in[26]; const float* be2 = (const float*)d_in[27];
  const float* g3  = (const float*)d_in[28]; const float* be3 = (const float*)d_in[29];
  float* out = (float*)d_out;

  // ---- workspace carve ----
  char* wsp = (char*)d_ws;
  size_t off = 0;
  auto alloc = [&](size_t bytes) -> void* {
    void* p = wsp + off;
    off = (off + bytes + 255) & ~(size_t)255;
    return p;
  };
  unsigned short* wq1b  = (unsigned short*)alloc(Lc * DD * 2);
  unsigned short* wo1b  = (unsigned short*)alloc(Lc * DD * 2);
  unsigned short* wq2b  = (unsigned short*)alloc(Lc * DD * 2);
  unsigned short* wo2b  = (unsigned short*)alloc(Lc * DD * 2);
  unsigned short* wkv1b = (unsigned short*)alloc(Lc * 2 * DD * 2);  // [l][wk;wv]
  unsigned short* wkv2b = (unsigned short*)alloc(Lc * 2 * DD * 2);
  unsigned short* wf1b  = (unsigned short*)alloc(Lc * FDl * 2);
  unsigned short* wf2b  = (unsigned short*)alloc(Lc * FDl * 2);
  float* bkv1c = (float*)alloc(Lc * 2048 * 4);
  float* bkv2c = (float*)alloc(Lc * 2048 * 4);
  unsigned short* encb  = (unsigned short*)alloc(BND * 2);
  unsigned short* featb = (unsigned short*)alloc(BND * 2);
  unsigned short* xb    = (unsigned short*)alloc(BND * 2);
  unsigned short* y1b   = (unsigned short*)alloc(BND * 2);
  unsigned short* y2b   = (unsigned short*)alloc(BND * 2);
  unsigned short* qb    = (unsigned short*)alloc(BND * 2);
  unsigned short* kvb   = (unsigned short*)alloc((long)Bc * Nc * 2048 * 2);  // [B*N, 2048]
  unsigned short* vtb   = (unsigned short*)alloc(BND * 2);
  unsigned short* ob    = (unsigned short*)alloc(BND * 2);
  unsigned short* hb    = (unsigned short*)alloc(BNF * 2);
  float* y1f = (float*)alloc(BND * 4);
  float* y2f = (float*)alloc(BND * 4);
  float* pre = (float*)alloc(BND * 4);
  (void)ws_size; (void)in_sizes; (void)n_in; (void)out_size;

  auto cast = [&](const float* src, unsigned short* dst, long n) {
    long n4 = n / 4;
    k_cast<<<dim3((unsigned)((n4 + 255) / 256)), dim3(256), 0, stream>>>(src, dst, n4);
  };
  auto cast2 = [&](const float* s1, const float* s2, unsigned short* dst) {
    k_cast2<<<dim3((unsigned)(Lc * 2 * DD / 4 / 256)), dim3(256), 0, stream>>>(s1, s2, dst);
  };
  auto bcat2 = [&](const float* b1, const float* b2, float* dst) {
    k_bcat2<<<dim3(Lc * 2048 / 256), dim3(256), 0, stream>>>(b1, b2, dst);
  };
  // 128x128 tile (Nout in {2048, 4096})
  auto gemm128 = [&](const unsigned short* A, const unsigned short* Wp, const float* bias,
                     const float* res, float* Cf, unsigned short* Cb,
                     int M, int Nout, int K, int lda, int ldb, int ldc, float scale, int relu) {
    gemm_bt<128, 128, 2, 2><<<dim3(Nout / 128, M / 128), dim3(256), 0, stream>>>(
        A, Wp, bias, res, Cf, Cb, K, lda, ldb, ldc, scale, relu);
  };
  // 128x64 tile (Nout=1024 -> grid 512 = 2 blocks/CU)
  auto gemm64 = [&](const unsigned short* A, const unsigned short* Wp, const float* bias,
                    const float* res, float* Cf, unsigned short* Cb,
                    int M, int Nout, int K, int lda, int ldb, int ldc, float scale, int relu) {
    gemm_bt<128, 64, 2, 2><<<dim3(Nout / 64, M / 128), dim3(256), 0, stream>>>(
        A, Wp, bias, res, Cf, Cb, K, lda, ldb, ldc, scale, relu);
  };
  auto flash = [&](const float* mask) {
    k_flash<<<dim3(Nc / QT, Bc * Hn), dim3(256), 0, stream>>>(qb, kvb, vtb, mask, ob, 2048);
  };
  auto ln = [&](const float* X, const float* gg, const float* bb, float* Yf, unsigned short* Yb) {
    k_ln<<<dim3(Bc * Nc), dim3(256), 0, stream>>>(X, gg, bb, Yf, Yb);
  };
  auto packvt = [&]() {
    k_packvt2<<<dim3(Nc / 64, Bc * Hn), dim3(256), 0, stream>>>(kvb, vtb);
  };

  // ---- upfront casts / concats ----
  cast(wq1, wq1b, Lc * DD); cast(wo1, wo1b, Lc * DD);
  cast(wq2, wq2b, Lc * DD); cast(wo2, wo2b, Lc * DD);
  cast2(wk1, wv1, wkv1b);   cast2(wk2, wv2, wkv2b);
  bcat2(bk1, bv1, bkv1c);   bcat2(bk2, bv2, bkv2c);
  cast(wf1, wf1b, Lc * FDl); cast(wf2, wf2b, Lc * FDl);
  cast(enc, encb, BND);

  const float qscale = 0.125f;  // HD^-0.5

  for (int l = 0; l < Lc; ++l) {
    const float* featl = feats + (long)l * BND;
    cast(featl, featb, BND);
    const unsigned short* kv = (l == 0) ? encb : xb;

    // ---- attn1: Q from feat, K/V from enc_out (fused KV proj) ----
    gemm64(featb, wq1b + l * DD, bq1 + l * Dc, nullptr, nullptr, qb,
           Bc * Nc, Dc, Dc, Dc, Dc, Dc, qscale, 0);
    gemm128(encb, wkv1b + (long)l * 2 * DD, bkv1c + l * 2048, nullptr, nullptr, kvb,
            Bc * Nc, 2048, Dc, Dc, Dc, 2048, 1.f, 0);
    packvt();
    flash(src_mask);
    gemm64(ob, wo1b + l * DD, bo1 + l * Dc, featl, pre, nullptr,
           Bc * Nc, Dc, Dc, Dc, Dc, Dc, 1.f, 0);
    ln(pre, g1 + l * Dc, be1 + l * Dc, y1f, y1b);

    // ---- attn2: Q from y, K/V from dec_out (fused KV proj) ----
    gemm64(y1b, wq2b + l * DD, bq2 + l * Dc, nullptr, nullptr, qb,
           Bc * Nc, Dc, Dc, Dc, Dc, Dc, qscale, 0);
    gemm128(kv, wkv2b + (long)l * 2 * DD, bkv2c + l * 2048, nullptr, nullptr, kvb,
            Bc * Nc, 2048, Dc, Dc, Dc, 2048, 1.f, 0);
    packvt();
    flash(trg_mask);
    gemm64(ob, wo2b + l * DD, bo2 + l * Dc, y1f, pre, nullptr,
           Bc * Nc, Dc, Dc, Dc, Dc, Dc, 1.f, 0);
    ln(pre, g2 + l * Dc, be2 + l * Dc, y2f, y2b);

    // ---- FFN ----
    gemm128(y2b, wf1b + (long)l * FDl, bf1 + l * Fc, nullptr, nullptr, hb,
            Bc * Nc, Fc, Dc, Dc, Dc, Fc, 1.f, 1);
    gemm64(hb, wf2b + (long)l * FDl, bf2 + l * Dc, y2f, pre, nullptr,
           Bc * Nc, Dc, Fc, Fc, Fc, Dc, 1.f, 0);
    ln(pre, g3 + l * Dc, be3 + l * Dc, out + (long)l * BND, xb);
  }
}